// Round 6
// baseline (253.054 us; speedup 1.0000x reference)
//
#include <hip/hip_runtime.h>
#include <hip/hip_cooperative_groups.h>

namespace cg = cooperative_groups;

#define DD 128

typedef _Float16 h8 __attribute__((ext_vector_type(8)));
typedef _Float16 h4v __attribute__((ext_vector_type(4)));
typedef float f4 __attribute__((ext_vector_type(4)));

// One cooperative kernel: W->fp16, zero cnt, count in-degrees, two-level scan,
// dis = rsqrt(deg), scatter edges into dst-grouped esrc. Replaces 6 launches.
// Grid is EXACTLY 256 blocks x 256 threads (1 block/CU — co-residency safe).
__global__ __launch_bounds__(256) void build_csr(
    const int* __restrict__ src, const int* __restrict__ dst,
    const float* __restrict__ W, _Float16* __restrict__ Wh,
    int* __restrict__ cnt, int* __restrict__ rowptr, float* __restrict__ dis,
    int* __restrict__ esrc, int* __restrict__ bsum, int E, int N) {
  cg::grid_group grid = cg::this_grid();
  const int tid = threadIdx.x, bid = blockIdx.x;
  const int gid = bid * 256 + tid;
  const int gsz = gridDim.x * 256;
  __shared__ int s[256];

  // phase 0: convert W, zero counters
  for (int i = gid; i < DD * DD; i += gsz) Wh[i] = (_Float16)W[i];
  for (int i = gid; i < N; i += gsz) cnt[i] = 0;
  grid.sync();

  // phase 1: count in-degree
  for (int e = gid; e < E; e += gsz) atomicAdd(cnt + dst[e], 1);
  grid.sync();

  // phase 2: block-local sum over contiguous chunk
  const int chunk = (N + gridDim.x - 1) / gridDim.x;   // 196 for N=50000
  const int lo = bid * chunk;
  const int hi = (lo + chunk < N) ? lo + chunk : N;
  int local = 0;
  for (int i = lo + tid; i < hi; i += 256) local += cnt[i];
  s[tid] = local;
  __syncthreads();
  for (int off = 128; off > 0; off >>= 1) {
    if (tid < off) s[tid] += s[tid + off];
    __syncthreads();
  }
  if (tid == 0) bsum[bid] = s[0];
  grid.sync();

  // phase 3: block 0 exclusive-scans the 256 block sums
  if (bid == 0) {
    const int v = bsum[tid];
    s[tid] = v;
    __syncthreads();
    for (int off = 1; off < 256; off <<= 1) {
      int t = (tid >= off) ? s[tid - off] : 0;
      __syncthreads();
      s[tid] += t;
      __syncthreads();
    }
    bsum[tid] = s[tid] - v;          // exclusive
    if (tid == 255) rowptr[N] = s[255];
  }
  grid.sync();

  // phase 4: local exclusive scan of the chunk -> rowptr; emit dis
  int base = bsum[bid];
  for (int t0 = lo; t0 < hi; t0 += 256) {
    const int i = t0 + tid;
    const int v = (i < hi) ? cnt[i] : 0;
    if (i < hi) dis[i] = rsqrtf((float)(v + 1));
    s[tid] = v;
    __syncthreads();
    for (int off = 1; off < 256; off <<= 1) {
      int t = (tid >= off) ? s[tid - off] : 0;
      __syncthreads();
      s[tid] += t;
      __syncthreads();
    }
    if (i < hi) rowptr[i] = base + s[tid] - v;
    base += s[255];
    __syncthreads();
  }
  grid.sync();

  // phase 5: scatter edges; cnt doubles as decrementing cursor (ends at 0)
  for (int e = gid; e < E; e += gsz) {
    const int t = dst[e];
    const int p = rowptr[t] + atomicAdd(cnt + t, -1) - 1;
    esrc[p] = src[e];
  }
}

// h16 = fp16(x @ W.T + b) via 16x16x32 f16 MFMA; whole W in wave registers, no LDS.
__global__ __launch_bounds__(256, 2) void gemm_mfma(const float* __restrict__ x,
    const _Float16* __restrict__ Wh, const float* __restrict__ bias,
    _Float16* __restrict__ h16, int nrt) {
  const int lane = threadIdx.x & 63;
  const int wid  = blockIdx.x * 4 + (threadIdx.x >> 6);
  const int nw   = gridDim.x * 4;
  const int lrow = lane & 15;          // A row / B col / C col
  const int lk   = (lane >> 4) << 3;   // k base within 32-wide k-step
  h8 wb[8][4];
#pragma unroll
  for (int jt = 0; jt < 8; ++jt)
#pragma unroll
    for (int ks = 0; ks < 4; ++ks)
      wb[jt][ks] = *(const h8*)(Wh + (jt * 16 + lrow) * DD + ks * 32 + lk);
  float bj[8];
#pragma unroll
  for (int jt = 0; jt < 8; ++jt) bj[jt] = bias[jt * 16 + lrow];
  const int srow = (lane >> 4) << 2;   // C row base = (lane>>4)*4 + reg
  for (int rt = wid; rt < nrt; rt += nw) {
    const int row0 = rt * 16;
    f4 acc[8];
#pragma unroll
    for (int jt = 0; jt < 8; ++jt) acc[jt] = (f4){0.f, 0.f, 0.f, 0.f};
#pragma unroll
    for (int ks = 0; ks < 4; ++ks) {
      const float* ap = x + (size_t)(row0 + lrow) * DD + ks * 32 + lk;
      const f4 a0 = *(const f4*)ap;
      const f4 a1 = *(const f4*)(ap + 4);
      h8 af;
      af[0] = (_Float16)a0.x; af[1] = (_Float16)a0.y;
      af[2] = (_Float16)a0.z; af[3] = (_Float16)a0.w;
      af[4] = (_Float16)a1.x; af[5] = (_Float16)a1.y;
      af[6] = (_Float16)a1.z; af[7] = (_Float16)a1.w;
#pragma unroll
      for (int jt = 0; jt < 8; ++jt)
        acc[jt] = __builtin_amdgcn_mfma_f32_16x16x32_f16(af, wb[jt][ks], acc[jt], 0, 0, 0);
    }
    _Float16* hp = h16 + (size_t)(row0 + srow) * DD + lrow;
#pragma unroll
    for (int jt = 0; jt < 8; ++jt)
#pragma unroll
      for (int r = 0; r < 4; ++r)
        hp[(size_t)r * DD + jt * 16] = (_Float16)(acc[jt][r] + bj[jt]);
  }
}

// per node: 32 threads each own 4 columns (8B fp16 gather); unroll-2 edge loop.
// out[n] = relu(h16[n]+root)/deg + dis[n] * sum_e relu(h16[src_e])*dis[src_e]
__global__ __launch_bounds__(256) void csr_agg(const int* __restrict__ esrc,
    const int* __restrict__ rowptr, const _Float16* __restrict__ h16,
    const float* __restrict__ dis, const float* __restrict__ root,
    float* __restrict__ out, int N) {
  int gid = blockIdx.x * blockDim.x + threadIdx.x;
  if (gid >= N * 32) return;
  const int n = gid >> 5, q = gid & 31;
  const float dt  = dis[n];
  const float inv = dt * dt;            // 1/deg
  const h4v* hv4 = reinterpret_cast<const h4v*>(h16);
  const float4 rv = reinterpret_cast<const float4*>(root)[q];
  const h4v hv = hv4[n * 32 + q];
  float4 acc;
  acc.x = fmaxf((float)hv[0] + rv.x, 0.0f) * inv;
  acc.y = fmaxf((float)hv[1] + rv.y, 0.0f) * inv;
  acc.z = fmaxf((float)hv[2] + rv.z, 0.0f) * inv;
  acc.w = fmaxf((float)hv[3] + rv.w, 0.0f) * inv;
  float4 ea = {0.f, 0.f, 0.f, 0.f};
  const int beg = rowptr[n], end = rowptr[n + 1];
  int k = beg;
  for (; k + 1 < end; k += 2) {
    const int s0 = esrc[k], s1 = esrc[k + 1];
    const float w0 = dis[s0], w1 = dis[s1];
    const h4v g0 = hv4[s0 * 32 + q];
    const h4v g1 = hv4[s1 * 32 + q];
    ea.x += fmaxf((float)g0[0], 0.0f) * w0;
    ea.y += fmaxf((float)g0[1], 0.0f) * w0;
    ea.z += fmaxf((float)g0[2], 0.0f) * w0;
    ea.w += fmaxf((float)g0[3], 0.0f) * w0;
    ea.x += fmaxf((float)g1[0], 0.0f) * w1;
    ea.y += fmaxf((float)g1[1], 0.0f) * w1;
    ea.z += fmaxf((float)g1[2], 0.0f) * w1;
    ea.w += fmaxf((float)g1[3], 0.0f) * w1;
  }
  if (k < end) {
    const int s0 = esrc[k];
    const float w0 = dis[s0];
    const h4v g0 = hv4[s0 * 32 + q];
    ea.x += fmaxf((float)g0[0], 0.0f) * w0;
    ea.y += fmaxf((float)g0[1], 0.0f) * w0;
    ea.z += fmaxf((float)g0[2], 0.0f) * w0;
    ea.w += fmaxf((float)g0[3], 0.0f) * w0;
  }
  acc.x += ea.x * dt;
  acc.y += ea.y * dt;
  acc.z += ea.z * dt;
  acc.w += ea.w * dt;
  reinterpret_cast<float4*>(out)[gid] = acc;
}

extern "C" void kernel_launch(void* const* d_in, const int* in_sizes, int n_in,
                              void* d_out, int out_size, void* d_ws, size_t ws_size,
                              hipStream_t stream) {
  const float* x    = (const float*)d_in[0];
  const int*   src  = (const int*)d_in[1];
  const int*   dst  = (const int*)d_in[2];
  const float* W    = (const float*)d_in[3];
  const float* bias = (const float*)d_in[4];
  const float* root = (const float*)d_in[5];
  float* out = (float*)d_out;
  int N = in_sizes[0] / DD;
  int E = in_sizes[1];

  char* ws = (char*)d_ws;
  size_t off = 0;
  _Float16* h16 = (_Float16*)(ws + off); off += (size_t)N * DD * 2;
  int*   cnt    = (int*)  (ws + off); off += (size_t)N * 4;
  float* dis    = (float*)(ws + off); off += (size_t)N * 4;
  int*   rowptr = (int*)  (ws + off); off += (size_t)(N + 2) * 4;
  int*   esrc   = (int*)  (ws + off); off += (size_t)E * 4;
  int*   bsum   = (int*)  (ws + off); off += 256 * 4;
  _Float16* Wh  = (_Float16*)(ws + off); off += (size_t)DD * DD * 2;

  void* args[] = {(void*)&src, (void*)&dst, (void*)&W, (void*)&Wh,
                  (void*)&cnt, (void*)&rowptr, (void*)&dis,
                  (void*)&esrc, (void*)&bsum, (void*)&E, (void*)&N};
  hipLaunchCooperativeKernel((void*)build_csr, dim3(256), dim3(256), args, 0, stream);
  gemm_mfma<<<391, 256, 0, stream>>>(x, Wh, bias, h16, N / 16);
  csr_agg<<<(N * 32 + 255) / 256, 256, 0, stream>>>(esrc, rowptr, h16, dis, root, out, N);
}

// Round 7
// 115.952 us; speedup vs baseline: 2.1824x; 2.1824x over previous
//
#include <hip/hip_runtime.h>

#define DD 128

typedef _Float16 h8 __attribute__((ext_vector_type(8)));
typedef _Float16 h4v __attribute__((ext_vector_type(4)));
typedef float f4 __attribute__((ext_vector_type(4)));

// prep: W (fp32) -> Wh (fp16), zero degree counters.
__global__ __launch_bounds__(256) void prep(const float* __restrict__ W,
    _Float16* __restrict__ Wh, int* __restrict__ cnt, int N) {
  const int gid = blockIdx.x * blockDim.x + threadIdx.x;
  const int stride = gridDim.x * blockDim.x;
  for (int i = gid; i < DD * DD; i += stride) Wh[i] = (_Float16)W[i];
  for (int i = gid; i < N; i += stride) cnt[i] = 0;
}

// h16 = fp16(x @ W.T + b) via 16x16x32 f16 MFMA; whole W in wave registers, no LDS.
// Prologue: in-degree counting rides here — atomics drain under other waves' work.
__global__ __launch_bounds__(256, 2) void gemm_mfma(const float* __restrict__ x,
    const _Float16* __restrict__ Wh, const float* __restrict__ bias,
    _Float16* __restrict__ h16, const int* __restrict__ dst,
    int* __restrict__ cnt, int E, int nrt) {
  const int gid = blockIdx.x * 256 + threadIdx.x;
  const int gsz = gridDim.x * 256;
  for (int e = gid; e < E; e += gsz) atomicAdd(cnt + dst[e], 1);

  const int lane = threadIdx.x & 63;
  const int wid  = blockIdx.x * 4 + (threadIdx.x >> 6);
  const int nw   = gridDim.x * 4;
  const int lrow = lane & 15;          // A row / B col / C col
  const int lk   = (lane >> 4) << 3;   // k base within 32-wide k-step
  h8 wb[8][4];
#pragma unroll
  for (int jt = 0; jt < 8; ++jt)
#pragma unroll
    for (int ks = 0; ks < 4; ++ks)
      wb[jt][ks] = *(const h8*)(Wh + (jt * 16 + lrow) * DD + ks * 32 + lk);
  float bj[8];
#pragma unroll
  for (int jt = 0; jt < 8; ++jt) bj[jt] = bias[jt * 16 + lrow];
  const int srow = (lane >> 4) << 2;   // C row base = (lane>>4)*4 + reg
  for (int rt = wid; rt < nrt; rt += nw) {
    const int row0 = rt * 16;
    f4 acc[8];
#pragma unroll
    for (int jt = 0; jt < 8; ++jt) acc[jt] = (f4){0.f, 0.f, 0.f, 0.f};
#pragma unroll
    for (int ks = 0; ks < 4; ++ks) {
      const float* ap = x + (size_t)(row0 + lrow) * DD + ks * 32 + lk;
      const f4 a0 = *(const f4*)ap;
      const f4 a1 = *(const f4*)(ap + 4);
      h8 af;
      af[0] = (_Float16)a0.x; af[1] = (_Float16)a0.y;
      af[2] = (_Float16)a0.z; af[3] = (_Float16)a0.w;
      af[4] = (_Float16)a1.x; af[5] = (_Float16)a1.y;
      af[6] = (_Float16)a1.z; af[7] = (_Float16)a1.w;
#pragma unroll
      for (int jt = 0; jt < 8; ++jt)
        acc[jt] = __builtin_amdgcn_mfma_f32_16x16x32_f16(af, wb[jt][ks], acc[jt], 0, 0, 0);
    }
    _Float16* hp = h16 + (size_t)(row0 + srow) * DD + lrow;
#pragma unroll
    for (int jt = 0; jt < 8; ++jt)
#pragma unroll
      for (int r = 0; r < 4; ++r)
        hp[(size_t)r * DD + jt * 16] = (_Float16)(acc[jt][r] + bj[jt]);
  }
}

// scan1: per-1024-chunk local exclusive scan of cnt -> rowptr, block sums -> bsum,
// dis = rsqrt(deg). (Global offsets boff added inline by consumers.)
__global__ __launch_bounds__(256) void scan1(const int* __restrict__ cnt,
    int* __restrict__ rowptr, int* __restrict__ bsum, float* __restrict__ dis, int N) {
  __shared__ int s[256];
  const int tid = threadIdx.x;
  const int idx = blockIdx.x * 1024 + tid * 4;
  int4 v = {0, 0, 0, 0};
  if (idx + 3 < N) v = *(const int4*)(cnt + idx);
  else {
    if (idx + 0 < N) v.x = cnt[idx];
    if (idx + 1 < N) v.y = cnt[idx + 1];
    if (idx + 2 < N) v.z = cnt[idx + 2];
  }
  if (idx + 0 < N) dis[idx + 0] = rsqrtf((float)(v.x + 1));
  if (idx + 1 < N) dis[idx + 1] = rsqrtf((float)(v.y + 1));
  if (idx + 2 < N) dis[idx + 2] = rsqrtf((float)(v.z + 1));
  if (idx + 3 < N) dis[idx + 3] = rsqrtf((float)(v.w + 1));
  const int mysum = v.x + v.y + v.z + v.w;
  s[tid] = mysum;
  __syncthreads();
  for (int off = 1; off < 256; off <<= 1) {
    int t = (tid >= off) ? s[tid - off] : 0;
    __syncthreads();
    s[tid] += t;
    __syncthreads();
  }
  if (tid == 255) bsum[blockIdx.x] = s[255];
  int p = s[tid] - mysum;
  if (idx + 0 < N) rowptr[idx + 0] = p; p += v.x;
  if (idx + 1 < N) rowptr[idx + 1] = p; p += v.y;
  if (idx + 2 < N) rowptr[idx + 2] = p; p += v.z;
  if (idx + 3 < N) rowptr[idx + 3] = p;
}

// scan2: exclusive scan of block sums -> boff; rowptr[N] = last block's local sum
// (so rowptr[n+1] + boff[(n+1)>>10] is E at n = N-1).
__global__ __launch_bounds__(256) void scan2(const int* __restrict__ bsum,
    int* __restrict__ boff, int* __restrict__ rowptr, int nb, int N) {
  __shared__ int s[256];
  const int tid = threadIdx.x;
  const int v = (tid < nb) ? bsum[tid] : 0;
  s[tid] = v;
  __syncthreads();
  for (int off = 1; off < 256; off <<= 1) {
    int t = (tid >= off) ? s[tid - off] : 0;
    __syncthreads();
    s[tid] += t;
    __syncthreads();
  }
  if (tid < nb) boff[tid] = s[tid] - v;
  if (tid == nb - 1) rowptr[N] = v;
}

// scatter edges into dst-grouped order; cnt doubles as a decrementing cursor.
__global__ void fill_csr(const int* __restrict__ src, const int* __restrict__ dst,
    const int* __restrict__ rowptr, const int* __restrict__ boff,
    int* __restrict__ cnt, int* __restrict__ esrc, int E) {
  int e = blockIdx.x * blockDim.x + threadIdx.x;
  if (e < E) {
    const int t = dst[e];
    const int p = rowptr[t] + boff[t >> 10] + atomicAdd(cnt + t, -1) - 1;
    esrc[p] = src[e];
  }
}

// per node: 32 threads each own 4 columns (8B fp16 gather); unroll-4 edge loop.
__global__ __launch_bounds__(256) void csr_agg(const int* __restrict__ esrc,
    const int* __restrict__ rowptr, const int* __restrict__ boff,
    const _Float16* __restrict__ h16, const float* __restrict__ dis,
    const float* __restrict__ root, float* __restrict__ out, int N) {
  int gid = blockIdx.x * blockDim.x + threadIdx.x;
  if (gid >= N * 32) return;
  const int n = gid >> 5, q = gid & 31;
  const float dt  = dis[n];
  const float inv = dt * dt;            // 1/deg
  const h4v* hv4 = reinterpret_cast<const h4v*>(h16);
  const float4 rv = reinterpret_cast<const float4*>(root)[q];
  const h4v hv = hv4[n * 32 + q];
  float4 acc;
  acc.x = fmaxf((float)hv[0] + rv.x, 0.0f) * inv;
  acc.y = fmaxf((float)hv[1] + rv.y, 0.0f) * inv;
  acc.z = fmaxf((float)hv[2] + rv.z, 0.0f) * inv;
  acc.w = fmaxf((float)hv[3] + rv.w, 0.0f) * inv;
  float4 ea = {0.f, 0.f, 0.f, 0.f};
  const int beg = rowptr[n] + boff[n >> 10];
  const int end = rowptr[n + 1] + boff[(n + 1) >> 10];
  int k = beg;
  for (; k + 3 < end; k += 4) {
    const int s0 = esrc[k], s1 = esrc[k + 1], s2 = esrc[k + 2], s3 = esrc[k + 3];
    const float w0 = dis[s0], w1 = dis[s1], w2 = dis[s2], w3 = dis[s3];
    const h4v g0 = hv4[s0 * 32 + q];
    const h4v g1 = hv4[s1 * 32 + q];
    const h4v g2 = hv4[s2 * 32 + q];
    const h4v g3 = hv4[s3 * 32 + q];
    ea.x += fmaxf((float)g0[0], 0.0f) * w0 + fmaxf((float)g1[0], 0.0f) * w1
          + fmaxf((float)g2[0], 0.0f) * w2 + fmaxf((float)g3[0], 0.0f) * w3;
    ea.y += fmaxf((float)g0[1], 0.0f) * w0 + fmaxf((float)g1[1], 0.0f) * w1
          + fmaxf((float)g2[1], 0.0f) * w2 + fmaxf((float)g3[1], 0.0f) * w3;
    ea.z += fmaxf((float)g0[2], 0.0f) * w0 + fmaxf((float)g1[2], 0.0f) * w1
          + fmaxf((float)g2[2], 0.0f) * w2 + fmaxf((float)g3[2], 0.0f) * w3;
    ea.w += fmaxf((float)g0[3], 0.0f) * w0 + fmaxf((float)g1[3], 0.0f) * w1
          + fmaxf((float)g2[3], 0.0f) * w2 + fmaxf((float)g3[3], 0.0f) * w3;
  }
  for (; k < end; ++k) {
    const int s0 = esrc[k];
    const float w0 = dis[s0];
    const h4v g0 = hv4[s0 * 32 + q];
    ea.x += fmaxf((float)g0[0], 0.0f) * w0;
    ea.y += fmaxf((float)g0[1], 0.0f) * w0;
    ea.z += fmaxf((float)g0[2], 0.0f) * w0;
    ea.w += fmaxf((float)g0[3], 0.0f) * w0;
  }
  acc.x += ea.x * dt;
  acc.y += ea.y * dt;
  acc.z += ea.z * dt;
  acc.w += ea.w * dt;
  reinterpret_cast<float4*>(out)[gid] = acc;
}

extern "C" void kernel_launch(void* const* d_in, const int* in_sizes, int n_in,
                              void* d_out, int out_size, void* d_ws, size_t ws_size,
                              hipStream_t stream) {
  const float* x    = (const float*)d_in[0];
  const int*   src  = (const int*)d_in[1];
  const int*   dst  = (const int*)d_in[2];
  const float* W    = (const float*)d_in[3];
  const float* bias = (const float*)d_in[4];
  const float* root = (const float*)d_in[5];
  float* out = (float*)d_out;
  const int N = in_sizes[0] / DD;
  const int E = in_sizes[1];

  char* ws = (char*)d_ws;
  size_t off = 0;
  _Float16* h16 = (_Float16*)(ws + off); off += (size_t)N * DD * 2;
  int*   cnt    = (int*)  (ws + off); off += (size_t)N * 4;
  float* dis    = (float*)(ws + off); off += (size_t)N * 4;
  int*   rowptr = (int*)  (ws + off); off += (size_t)(N + 2) * 4;
  int*   esrc   = (int*)  (ws + off); off += (size_t)E * 4;
  int*   bsum   = (int*)  (ws + off); off += 256 * 4;
  int*   boff   = (int*)  (ws + off); off += 256 * 4;
  _Float16* Wh  = (_Float16*)(ws + off); off += (size_t)DD * DD * 2;

  const int nb = (N + 1023) / 1024;  // 49
  prep<<<256, 256, 0, stream>>>(W, Wh, cnt, N);
  gemm_mfma<<<391, 256, 0, stream>>>(x, Wh, bias, h16, dst, cnt, E, N / 16);
  scan1<<<nb, 256, 0, stream>>>(cnt, rowptr, bsum, dis, N);
  scan2<<<1, 256, 0, stream>>>(bsum, boff, rowptr, nb, N);
  fill_csr<<<(E + 255) / 256, 256, 0, stream>>>(src, dst, rowptr, boff, cnt, esrc, E);
  csr_agg<<<(N * 32 + 255) / 256, 256, 0, stream>>>(esrc, rowptr, boff, h16, dis, root, out, N);
}

// Round 8
// 115.342 us; speedup vs baseline: 2.1939x; 1.0053x over previous
//
#include <hip/hip_runtime.h>

#define DD 128

typedef _Float16 h8 __attribute__((ext_vector_type(8)));
typedef _Float16 h4v __attribute__((ext_vector_type(4)));
typedef float f4 __attribute__((ext_vector_type(4)));

// prep: W (fp32) -> Wh (fp16), zero degree counters.
__global__ __launch_bounds__(256) void prep(const float* __restrict__ W,
    _Float16* __restrict__ Wh, int* __restrict__ cnt, int N) {
  const int gid = blockIdx.x * blockDim.x + threadIdx.x;
  const int stride = gridDim.x * blockDim.x;
  for (int i = gid; i < DD * DD; i += stride) Wh[i] = (_Float16)W[i];
  for (int i = gid; i < N; i += stride) cnt[i] = 0;
}

// h16 = fp16(x @ W.T + b). Work unit = 16 rows x 64 cols (16 MFMAs) so the grid
// reaches ~6 waves/SIMD — R7 showed 11.6% occupancy / 1.5 waves/SIMD was the
// bottleneck (VALUBusy 1.5%, latency-bound). In-degree atomic prologue rides here.
__global__ __launch_bounds__(256) void gemm_mfma(const float* __restrict__ x,
    const _Float16* __restrict__ Wh, const float* __restrict__ bias,
    _Float16* __restrict__ h16, const int* __restrict__ dst,
    int* __restrict__ cnt, int E, int nu) {
  const int gid = blockIdx.x * 256 + threadIdx.x;
  const int gsz = gridDim.x * 256;
  for (int e = gid; e < E; e += gsz) atomicAdd(cnt + dst[e], 1);

  const int lane = threadIdx.x & 63;
  const int wid  = blockIdx.x * 4 + (threadIdx.x >> 6);
  const int nw   = gridDim.x * 4;
  const int lrow = lane & 15;          // A row / B col / C col (within 16)
  const int lk   = (lane >> 4) << 3;   // k base within 32-wide k-step
  const int srow = (lane >> 4) << 2;   // C row base = (lane>>4)*4 + reg
  for (int u = wid; u < nu; u += nw) {
    const int rt = u >> 1;             // 16-row tile
    const int jh = (u & 1) * 4;        // column half: j-tiles [jh, jh+4)
    const int row0 = rt * 16;
    h8 wb[4][4];
    float bj[4];
#pragma unroll
    for (int jt = 0; jt < 4; ++jt) {
      bj[jt] = bias[(jh + jt) * 16 + lrow];
#pragma unroll
      for (int ks = 0; ks < 4; ++ks)
        wb[jt][ks] = *(const h8*)(Wh + ((jh + jt) * 16 + lrow) * DD + ks * 32 + lk);
    }
    f4 acc[4];
#pragma unroll
    for (int jt = 0; jt < 4; ++jt) acc[jt] = (f4){0.f, 0.f, 0.f, 0.f};
#pragma unroll
    for (int ks = 0; ks < 4; ++ks) {
      const float* ap = x + (size_t)(row0 + lrow) * DD + ks * 32 + lk;
      const f4 a0 = *(const f4*)ap;
      const f4 a1 = *(const f4*)(ap + 4);
      h8 af;
      af[0] = (_Float16)a0.x; af[1] = (_Float16)a0.y;
      af[2] = (_Float16)a0.z; af[3] = (_Float16)a0.w;
      af[4] = (_Float16)a1.x; af[5] = (_Float16)a1.y;
      af[6] = (_Float16)a1.z; af[7] = (_Float16)a1.w;
#pragma unroll
      for (int jt = 0; jt < 4; ++jt)
        acc[jt] = __builtin_amdgcn_mfma_f32_16x16x32_f16(af, wb[jt][ks], acc[jt], 0, 0, 0);
    }
    _Float16* hp = h16 + (size_t)(row0 + srow) * DD + lrow;
#pragma unroll
    for (int jt = 0; jt < 4; ++jt)
#pragma unroll
      for (int r = 0; r < 4; ++r)
        hp[(size_t)r * DD + (jh + jt) * 16] = (_Float16)(acc[jt][r] + bj[jt]);
  }
}

// scan1: per-1024-chunk local exclusive scan of cnt -> rowptr, block sums -> bsum,
// dis = rsqrt(deg). (Global offsets boff added inline by consumers.)
__global__ __launch_bounds__(256) void scan1(const int* __restrict__ cnt,
    int* __restrict__ rowptr, int* __restrict__ bsum, float* __restrict__ dis, int N) {
  __shared__ int s[256];
  const int tid = threadIdx.x;
  const int idx = blockIdx.x * 1024 + tid * 4;
  int4 v = {0, 0, 0, 0};
  if (idx + 3 < N) v = *(const int4*)(cnt + idx);
  else {
    if (idx + 0 < N) v.x = cnt[idx];
    if (idx + 1 < N) v.y = cnt[idx + 1];
    if (idx + 2 < N) v.z = cnt[idx + 2];
  }
  if (idx + 0 < N) dis[idx + 0] = rsqrtf((float)(v.x + 1));
  if (idx + 1 < N) dis[idx + 1] = rsqrtf((float)(v.y + 1));
  if (idx + 2 < N) dis[idx + 2] = rsqrtf((float)(v.z + 1));
  if (idx + 3 < N) dis[idx + 3] = rsqrtf((float)(v.w + 1));
  const int mysum = v.x + v.y + v.z + v.w;
  s[tid] = mysum;
  __syncthreads();
  for (int off = 1; off < 256; off <<= 1) {
    int t = (tid >= off) ? s[tid - off] : 0;
    __syncthreads();
    s[tid] += t;
    __syncthreads();
  }
  if (tid == 255) bsum[blockIdx.x] = s[255];
  int p = s[tid] - mysum;
  if (idx + 0 < N) rowptr[idx + 0] = p; p += v.x;
  if (idx + 1 < N) rowptr[idx + 1] = p; p += v.y;
  if (idx + 2 < N) rowptr[idx + 2] = p; p += v.z;
  if (idx + 3 < N) rowptr[idx + 3] = p;
}

// scan2: exclusive scan of block sums -> boff; rowptr[N] = last block's local sum.
__global__ __launch_bounds__(256) void scan2(const int* __restrict__ bsum,
    int* __restrict__ boff, int* __restrict__ rowptr, int nb, int N) {
  __shared__ int s[256];
  const int tid = threadIdx.x;
  const int v = (tid < nb) ? bsum[tid] : 0;
  s[tid] = v;
  __syncthreads();
  for (int off = 1; off < 256; off <<= 1) {
    int t = (tid >= off) ? s[tid - off] : 0;
    __syncthreads();
    s[tid] += t;
    __syncthreads();
  }
  if (tid < nb) boff[tid] = s[tid] - v;
  if (tid == nb - 1) rowptr[N] = v;
}

// scatter edges into dst-grouped order; cnt doubles as a decrementing cursor.
__global__ void fill_csr(const int* __restrict__ src, const int* __restrict__ dst,
    const int* __restrict__ rowptr, const int* __restrict__ boff,
    int* __restrict__ cnt, int* __restrict__ esrc, int E) {
  int e = blockIdx.x * blockDim.x + threadIdx.x;
  if (e < E) {
    const int t = dst[e];
    const int p = rowptr[t] + boff[t >> 10] + atomicAdd(cnt + t, -1) - 1;
    esrc[p] = src[e];
  }
}

// per node: 32 threads each own 4 columns (8B fp16 gather); unroll-4 edge loop.
__global__ __launch_bounds__(256) void csr_agg(const int* __restrict__ esrc,
    const int* __restrict__ rowptr, const int* __restrict__ boff,
    const _Float16* __restrict__ h16, const float* __restrict__ dis,
    const float* __restrict__ root, float* __restrict__ out, int N) {
  int gid = blockIdx.x * blockDim.x + threadIdx.x;
  if (gid >= N * 32) return;
  const int n = gid >> 5, q = gid & 31;
  const float dt  = dis[n];
  const float inv = dt * dt;            // 1/deg
  const h4v* hv4 = reinterpret_cast<const h4v*>(h16);
  const float4 rv = reinterpret_cast<const float4*>(root)[q];
  const h4v hv = hv4[n * 32 + q];
  float4 acc;
  acc.x = fmaxf((float)hv[0] + rv.x, 0.0f) * inv;
  acc.y = fmaxf((float)hv[1] + rv.y, 0.0f) * inv;
  acc.z = fmaxf((float)hv[2] + rv.z, 0.0f) * inv;
  acc.w = fmaxf((float)hv[3] + rv.w, 0.0f) * inv;
  float4 ea = {0.f, 0.f, 0.f, 0.f};
  const int beg = rowptr[n] + boff[n >> 10];
  const int end = rowptr[n + 1] + boff[(n + 1) >> 10];
  int k = beg;
  for (; k + 3 < end; k += 4) {
    const int s0 = esrc[k], s1 = esrc[k + 1], s2 = esrc[k + 2], s3 = esrc[k + 3];
    const float w0 = dis[s0], w1 = dis[s1], w2 = dis[s2], w3 = dis[s3];
    const h4v g0 = hv4[s0 * 32 + q];
    const h4v g1 = hv4[s1 * 32 + q];
    const h4v g2 = hv4[s2 * 32 + q];
    const h4v g3 = hv4[s3 * 32 + q];
    ea.x += fmaxf((float)g0[0], 0.0f) * w0 + fmaxf((float)g1[0], 0.0f) * w1
          + fmaxf((float)g2[0], 0.0f) * w2 + fmaxf((float)g3[0], 0.0f) * w3;
    ea.y += fmaxf((float)g0[1], 0.0f) * w0 + fmaxf((float)g1[1], 0.0f) * w1
          + fmaxf((float)g2[1], 0.0f) * w2 + fmaxf((float)g3[1], 0.0f) * w3;
    ea.z += fmaxf((float)g0[2], 0.0f) * w0 + fmaxf((float)g1[2], 0.0f) * w1
          + fmaxf((float)g2[2], 0.0f) * w2 + fmaxf((float)g3[2], 0.0f) * w3;
    ea.w += fmaxf((float)g0[3], 0.0f) * w0 + fmaxf((float)g1[3], 0.0f) * w1
          + fmaxf((float)g2[3], 0.0f) * w2 + fmaxf((float)g3[3], 0.0f) * w3;
  }
  for (; k < end; ++k) {
    const int s0 = esrc[k];
    const float w0 = dis[s0];
    const h4v g0 = hv4[s0 * 32 + q];
    ea.x += fmaxf((float)g0[0], 0.0f) * w0;
    ea.y += fmaxf((float)g0[1], 0.0f) * w0;
    ea.z += fmaxf((float)g0[2], 0.0f) * w0;
    ea.w += fmaxf((float)g0[3], 0.0f) * w0;
  }
  acc.x += ea.x * dt;
  acc.y += ea.y * dt;
  acc.z += ea.z * dt;
  acc.w += ea.w * dt;
  reinterpret_cast<float4*>(out)[gid] = acc;
}

extern "C" void kernel_launch(void* const* d_in, const int* in_sizes, int n_in,
                              void* d_out, int out_size, void* d_ws, size_t ws_size,
                              hipStream_t stream) {
  const float* x    = (const float*)d_in[0];
  const int*   src  = (const int*)d_in[1];
  const int*   dst  = (const int*)d_in[2];
  const float* W    = (const float*)d_in[3];
  const float* bias = (const float*)d_in[4];
  const float* root = (const float*)d_in[5];
  float* out = (float*)d_out;
  const int N = in_sizes[0] / DD;
  const int E = in_sizes[1];

  char* ws = (char*)d_ws;
  size_t off = 0;
  _Float16* h16 = (_Float16*)(ws + off); off += (size_t)N * DD * 2;
  int*   cnt    = (int*)  (ws + off); off += (size_t)N * 4;
  float* dis    = (float*)(ws + off); off += (size_t)N * 4;
  int*   rowptr = (int*)  (ws + off); off += (size_t)(N + 2) * 4;
  int*   esrc   = (int*)  (ws + off); off += (size_t)E * 4;
  int*   bsum   = (int*)  (ws + off); off += 256 * 4;
  int*   boff   = (int*)  (ws + off); off += 256 * 4;
  _Float16* Wh  = (_Float16*)(ws + off); off += (size_t)DD * DD * 2;

  const int nb = (N + 1023) / 1024;  // 49
  const int nu = (N / 16) * 2;       // 6250 work units (16 rows x 64 cols)
  prep<<<256, 256, 0, stream>>>(W, Wh, cnt, N);
  gemm_mfma<<<(nu + 3) / 4, 256, 0, stream>>>(x, Wh, bias, h16, dst, cnt, E, nu);
  scan1<<<nb, 256, 0, stream>>>(cnt, rowptr, bsum, dis, N);
  scan2<<<1, 256, 0, stream>>>(bsum, boff, rowptr, nb, N);
  fill_csr<<<(E + 255) / 256, 256, 0, stream>>>(src, dst, rowptr, boff, cnt, esrc, E);
  csr_agg<<<(N * 32 + 255) / 256, 256, 0, stream>>>(esrc, rowptr, boff, h16, dis, root, out, N);
}

// Round 9
// 113.555 us; speedup vs baseline: 2.2285x; 1.0157x over previous
//
#include <hip/hip_runtime.h>

#define DD 128

typedef _Float16 h8 __attribute__((ext_vector_type(8)));
typedef _Float16 h4v __attribute__((ext_vector_type(4)));
typedef float f4 __attribute__((ext_vector_type(4)));

// prep: zero degree counters.
__global__ __launch_bounds__(256) void prep(int* __restrict__ cnt, int N) {
  const int gid = blockIdx.x * blockDim.x + threadIdx.x;
  const int stride = gridDim.x * blockDim.x;
  for (int i = gid; i < N; i += stride) cnt[i] = 0;
}

// h16 = fp16(x @ W.T + b). Block = 32 rows. x staged to LDS via global_load_lds
// (linear dest, source 16B-group-swizzled cg^=(row&7) so MFMA-layout ds_read_b128
// is bank-balanced). Wave w owns cols [w*32, w*32+32). C staged through LDS for
// full-line coalesced stores (R8: strided 2B stores caused 31MB write-amp).
// In-degree atomic prologue rides here.
__global__ __launch_bounds__(256) void gemm_mfma(const float* __restrict__ x,
    const float* __restrict__ W, const float* __restrict__ bias,
    _Float16* __restrict__ h16, const int* __restrict__ dst,
    int* __restrict__ cnt, int E, int N) {
  __shared__ __align__(16) char lds[16384 + 4096];   // xs 32x512B | cs 16x256B
  const int tid = threadIdx.x;
  const int gid = blockIdx.x * 256 + tid;
  const int gsz = gridDim.x * 256;
  for (int e = gid; e < E; e += gsz) atomicAdd(cnt + dst[e], 1);

  const int lane = tid & 63;
  const int w    = tid >> 6;          // wave id -> cols w*32..+32
  const int lrow = lane & 15;
  const int srow = (lane >> 4) << 2;

  // W fragments (fp32 -> fp16), loaded once per kernel
  h8 wb[2][4];
  float bj[2];
#pragma unroll
  for (int jt = 0; jt < 2; ++jt) {
    const int col = w * 32 + jt * 16 + lrow;
    bj[jt] = bias[col];
#pragma unroll
    for (int ks = 0; ks < 4; ++ks) {
      const float* wp = W + col * DD + ks * 32 + (lane >> 4) * 8;
      const f4 w0 = *(const f4*)wp;
      const f4 w1 = *(const f4*)(wp + 4);
      h8 f;
      f[0]=(_Float16)w0.x; f[1]=(_Float16)w0.y; f[2]=(_Float16)w0.z; f[3]=(_Float16)w0.w;
      f[4]=(_Float16)w1.x; f[5]=(_Float16)w1.y; f[6]=(_Float16)w1.z; f[7]=(_Float16)w1.w;
      wb[jt][ks] = f;
    }
  }

  const int row0 = blockIdx.x * 32;
  // stage 32 rows x 512B in 4 rounds (256 thr x 16B); LDS linear, source swizzled
#pragma unroll
  for (int i = 0; i < 4; ++i) {
    const int ol = i * 4096 + tid * 16;   // linear LDS byte offset
    const int r  = ol >> 9;               // staged row 0..31
    const int cg = (ol >> 4) & 31;        // 16B col-group
    int grow = row0 + r; if (grow >= N) grow = N - 1;   // tail clamp
    const char* src = (const char*)x + (size_t)grow * 512 + ((cg ^ (r & 7)) << 4);
    __builtin_amdgcn_global_load_lds(
        (const __attribute__((address_space(1))) void*)src,
        (__attribute__((address_space(3))) void*)(lds + i * 4096 + ((tid >> 6) << 10)),
        16, 0, 0);
  }
  __syncthreads();

  _Float16* cs = (_Float16*)(lds + 16384);
#pragma unroll
  for (int rt = 0; rt < 2; ++rt) {
    const int rowbase = row0 + rt * 16;
    if (rowbase >= N) break;             // block-uniform (tail block only)
    f4 acc[2] = {(f4){0.f,0.f,0.f,0.f}, (f4){0.f,0.f,0.f,0.f}};
#pragma unroll
    for (int ks = 0; ks < 4; ++ks) {
      const int r   = rt * 16 + lrow;
      const int cg0 = ks * 8 + (lane >> 4) * 2;
      const f4 a0 = *(const f4*)(lds + r * 512 + ((cg0 ^ (r & 7)) << 4));
      const f4 a1 = *(const f4*)(lds + r * 512 + (((cg0 + 1) ^ (r & 7)) << 4));
      h8 af;
      af[0]=(_Float16)a0.x; af[1]=(_Float16)a0.y; af[2]=(_Float16)a0.z; af[3]=(_Float16)a0.w;
      af[4]=(_Float16)a1.x; af[5]=(_Float16)a1.y; af[6]=(_Float16)a1.z; af[7]=(_Float16)a1.w;
      acc[0] = __builtin_amdgcn_mfma_f32_16x16x32_f16(af, wb[0][ks], acc[0], 0, 0, 0);
      acc[1] = __builtin_amdgcn_mfma_f32_16x16x32_f16(af, wb[1][ks], acc[1], 0, 0, 0);
    }
#pragma unroll
    for (int jt = 0; jt < 2; ++jt)
#pragma unroll
      for (int r = 0; r < 4; ++r)
        cs[(srow + r) * DD + w * 32 + jt * 16 + lrow] = (_Float16)(acc[jt][r] + bj[jt]);
    __syncthreads();
    const int frow = rowbase + (tid >> 4);
    if (frow < N) {
      const f4 v = *(const f4*)((char*)cs + tid * 16);
      *(f4*)((char*)h16 + (size_t)frow * 256 + (tid & 15) * 16) = v;
    }
    __syncthreads();
  }
}

// scan1: per-1024-chunk local exclusive scan of cnt -> rowptr, block sums -> bsum,
// dis = rsqrt(deg). (Global offsets boff added inline by consumers.)
__global__ __launch_bounds__(256) void scan1(const int* __restrict__ cnt,
    int* __restrict__ rowptr, int* __restrict__ bsum, float* __restrict__ dis, int N) {
  __shared__ int s[256];
  const int tid = threadIdx.x;
  const int idx = blockIdx.x * 1024 + tid * 4;
  int4 v = {0, 0, 0, 0};
  if (idx + 3 < N) v = *(const int4*)(cnt + idx);
  else {
    if (idx + 0 < N) v.x = cnt[idx];
    if (idx + 1 < N) v.y = cnt[idx + 1];
    if (idx + 2 < N) v.z = cnt[idx + 2];
  }
  if (idx + 0 < N) dis[idx + 0] = rsqrtf((float)(v.x + 1));
  if (idx + 1 < N) dis[idx + 1] = rsqrtf((float)(v.y + 1));
  if (idx + 2 < N) dis[idx + 2] = rsqrtf((float)(v.z + 1));
  if (idx + 3 < N) dis[idx + 3] = rsqrtf((float)(v.w + 1));
  const int mysum = v.x + v.y + v.z + v.w;
  s[tid] = mysum;
  __syncthreads();
  for (int off = 1; off < 256; off <<= 1) {
    int t = (tid >= off) ? s[tid - off] : 0;
    __syncthreads();
    s[tid] += t;
    __syncthreads();
  }
  if (tid == 255) bsum[blockIdx.x] = s[255];
  int p = s[tid] - mysum;
  if (idx + 0 < N) rowptr[idx + 0] = p; p += v.x;
  if (idx + 1 < N) rowptr[idx + 1] = p; p += v.y;
  if (idx + 2 < N) rowptr[idx + 2] = p; p += v.z;
  if (idx + 3 < N) rowptr[idx + 3] = p;
}

// scan2: exclusive scan of block sums -> boff; rowptr[N] = last block's local sum.
__global__ __launch_bounds__(256) void scan2(const int* __restrict__ bsum,
    int* __restrict__ boff, int* __restrict__ rowptr, int nb, int N) {
  __shared__ int s[256];
  const int tid = threadIdx.x;
  const int v = (tid < nb) ? bsum[tid] : 0;
  s[tid] = v;
  __syncthreads();
  for (int off = 1; off < 256; off <<= 1) {
    int t = (tid >= off) ? s[tid - off] : 0;
    __syncthreads();
    s[tid] += t;
    __syncthreads();
  }
  if (tid < nb) boff[tid] = s[tid] - v;
  if (tid == nb - 1) rowptr[N] = v;
}

// scatter edges into dst-grouped order; cnt doubles as a decrementing cursor.
__global__ void fill_csr(const int* __restrict__ src, const int* __restrict__ dst,
    const int* __restrict__ rowptr, const int* __restrict__ boff,
    int* __restrict__ cnt, int* __restrict__ esrc, int E) {
  int e = blockIdx.x * blockDim.x + threadIdx.x;
  if (e < E) {
    const int t = dst[e];
    const int p = rowptr[t] + boff[t >> 10] + atomicAdd(cnt + t, -1) - 1;
    esrc[p] = src[e];
  }
}

// per node: 32 threads each own 4 columns (8B fp16 gather); unroll-4 edge loop.
__global__ __launch_bounds__(256) void csr_agg(const int* __restrict__ esrc,
    const int* __restrict__ rowptr, const int* __restrict__ boff,
    const _Float16* __restrict__ h16, const float* __restrict__ dis,
    const float* __restrict__ root, float* __restrict__ out, int N) {
  int gid = blockIdx.x * blockDim.x + threadIdx.x;
  if (gid >= N * 32) return;
  const int n = gid >> 5, q = gid & 31;
  const float dt  = dis[n];
  const float inv = dt * dt;            // 1/deg
  const h4v* hv4 = reinterpret_cast<const h4v*>(h16);
  const float4 rv = reinterpret_cast<const float4*>(root)[q];
  const h4v hv = hv4[n * 32 + q];
  float4 acc;
  acc.x = fmaxf((float)hv[0] + rv.x, 0.0f) * inv;
  acc.y = fmaxf((float)hv[1] + rv.y, 0.0f) * inv;
  acc.z = fmaxf((float)hv[2] + rv.z, 0.0f) * inv;
  acc.w = fmaxf((float)hv[3] + rv.w, 0.0f) * inv;
  float4 ea = {0.f, 0.f, 0.f, 0.f};
  const int beg = rowptr[n] + boff[n >> 10];
  const int end = rowptr[n + 1] + boff[(n + 1) >> 10];
  int k = beg;
  for (; k + 3 < end; k += 4) {
    const int s0 = esrc[k], s1 = esrc[k + 1], s2 = esrc[k + 2], s3 = esrc[k + 3];
    const float w0 = dis[s0], w1 = dis[s1], w2 = dis[s2], w3 = dis[s3];
    const h4v g0 = hv4[s0 * 32 + q];
    const h4v g1 = hv4[s1 * 32 + q];
    const h4v g2 = hv4[s2 * 32 + q];
    const h4v g3 = hv4[s3 * 32 + q];
    ea.x += fmaxf((float)g0[0], 0.0f) * w0 + fmaxf((float)g1[0], 0.0f) * w1
          + fmaxf((float)g2[0], 0.0f) * w2 + fmaxf((float)g3[0], 0.0f) * w3;
    ea.y += fmaxf((float)g0[1], 0.0f) * w0 + fmaxf((float)g1[1], 0.0f) * w1
          + fmaxf((float)g2[1], 0.0f) * w2 + fmaxf((float)g3[1], 0.0f) * w3;
    ea.z += fmaxf((float)g0[2], 0.0f) * w0 + fmaxf((float)g1[2], 0.0f) * w1
          + fmaxf((float)g2[2], 0.0f) * w2 + fmaxf((float)g3[2], 0.0f) * w3;
    ea.w += fmaxf((float)g0[3], 0.0f) * w0 + fmaxf((float)g1[3], 0.0f) * w1
          + fmaxf((float)g2[3], 0.0f) * w2 + fmaxf((float)g3[3], 0.0f) * w3;
  }
  for (; k < end; ++k) {
    const int s0 = esrc[k];
    const float w0 = dis[s0];
    const h4v g0 = hv4[s0 * 32 + q];
    ea.x += fmaxf((float)g0[0], 0.0f) * w0;
    ea.y += fmaxf((float)g0[1], 0.0f) * w0;
    ea.z += fmaxf((float)g0[2], 0.0f) * w0;
    ea.w += fmaxf((float)g0[3], 0.0f) * w0;
  }
  acc.x += ea.x * dt;
  acc.y += ea.y * dt;
  acc.z += ea.z * dt;
  acc.w += ea.w * dt;
  reinterpret_cast<float4*>(out)[gid] = acc;
}

extern "C" void kernel_launch(void* const* d_in, const int* in_sizes, int n_in,
                              void* d_out, int out_size, void* d_ws, size_t ws_size,
                              hipStream_t stream) {
  const float* x    = (const float*)d_in[0];
  const int*   src  = (const int*)d_in[1];
  const int*   dst  = (const int*)d_in[2];
  const float* W    = (const float*)d_in[3];
  const float* bias = (const float*)d_in[4];
  const float* root = (const float*)d_in[5];
  float* out = (float*)d_out;
  const int N = in_sizes[0] / DD;
  const int E = in_sizes[1];

  char* ws = (char*)d_ws;
  size_t off = 0;
  _Float16* h16 = (_Float16*)(ws + off); off += (size_t)N * DD * 2;
  int*   cnt    = (int*)  (ws + off); off += (size_t)N * 4;
  float* dis    = (float*)(ws + off); off += (size_t)N * 4;
  int*   rowptr = (int*)  (ws + off); off += (size_t)(N + 2) * 4;
  int*   esrc   = (int*)  (ws + off); off += (size_t)E * 4;
  int*   bsum   = (int*)  (ws + off); off += 256 * 4;
  int*   boff   = (int*)  (ws + off); off += 256 * 4;

  const int nb  = (N + 1023) / 1024;   // 49
  const int nbt = (N + 31) / 32;       // 1563 row-tiles of 32
  prep<<<128, 256, 0, stream>>>(cnt, N);
  gemm_mfma<<<nbt, 256, 0, stream>>>(x, W, bias, h16, dst, cnt, E, N);
  scan1<<<nb, 256, 0, stream>>>(cnt, rowptr, bsum, dis, N);
  scan2<<<1, 256, 0, stream>>>(bsum, boff, rowptr, nb, N);
  fill_csr<<<(E + 255) / 256, 256, 0, stream>>>(src, dst, rowptr, boff, cnt, esrc, E);
  csr_agg<<<(N * 32 + 255) / 256, 256, 0, stream>>>(esrc, rowptr, boff, h16, dis, root, out, N);
}

// Round 10
// 108.079 us; speedup vs baseline: 2.3414x; 1.0507x over previous
//
#include <hip/hip_runtime.h>

#define DD 128

typedef _Float16 h8 __attribute__((ext_vector_type(8)));
typedef _Float16 h4v __attribute__((ext_vector_type(4)));
typedef float f4 __attribute__((ext_vector_type(4)));

// prep: W (fp32) -> Wh (fp16), zero degree counters.
__global__ __launch_bounds__(256) void prep(const float* __restrict__ W,
    _Float16* __restrict__ Wh, int* __restrict__ cnt, int N) {
  const int gid = blockIdx.x * blockDim.x + threadIdx.x;
  const int stride = gridDim.x * blockDim.x;
  for (int i = gid; i < DD * DD; i += stride) Wh[i] = (_Float16)W[i];
  for (int i = gid; i < N; i += stride) cnt[i] = 0;
}

// h16 = fp16(x @ W.T + b). Block = 64 rows. Wh (32KB) staged linearly via
// global_load_lds (coalesced) and read as fragments ONCE per block — R7/R8/R9
// all stalled at ~43us because W was re-gathered as 512B-strided fragments
// per tile (~300MB of L2 line traffic). x staged source-swizzled (cg^=(r&7));
// C staged through LDS for coalesced stores. In-degree atomic prologue rides here.
__global__ __launch_bounds__(256) void gemm_mfma(const float* __restrict__ x,
    const _Float16* __restrict__ Wh, const float* __restrict__ bias,
    _Float16* __restrict__ h16, const int* __restrict__ dst,
    int* __restrict__ cnt, int E, int N) {
  __shared__ __align__(16) char lds[32768 + 32768 + 4096]; // xs | whs | cs
  const int tid = threadIdx.x;
  const int gid = blockIdx.x * 256 + tid;
  const int gsz = gridDim.x * 256;
  for (int e = gid; e < E; e += gsz) atomicAdd(cnt + dst[e], 1);

  const int lane = tid & 63;
  const int w    = tid >> 6;          // wave id -> cols w*32..+32
  const int lrow = lane & 15;
  const int srow = (lane >> 4) << 2;
  const int row0 = blockIdx.x * 64;

  // stage Wh: 32KB linear, fully coalesced
#pragma unroll
  for (int i = 0; i < 8; ++i) {
    const char* s = (const char*)Wh + i * 4096 + tid * 16;
    __builtin_amdgcn_global_load_lds(
        (const __attribute__((address_space(1))) void*)s,
        (__attribute__((address_space(3))) void*)(lds + 32768 + i * 4096 + ((tid >> 6) << 10)),
        16, 0, 0);
  }
  // stage x: 64 rows x 512B; LDS linear, global source 16B-group swizzled
#pragma unroll
  for (int i = 0; i < 8; ++i) {
    const int ol = i * 4096 + tid * 16;
    const int r  = ol >> 9;               // staged row 0..63
    const int cg = (ol >> 4) & 31;        // 16B col-group
    int grow = row0 + r; if (grow >= N) grow = N - 1;
    const char* s = (const char*)x + (size_t)grow * 512 + ((cg ^ (r & 7)) << 4);
    __builtin_amdgcn_global_load_lds(
        (const __attribute__((address_space(1))) void*)s,
        (__attribute__((address_space(3))) void*)(lds + i * 4096 + ((tid >> 6) << 10)),
        16, 0, 0);
  }
  __syncthreads();

  // W fragments + bias from LDS, once per block (one-time 16-way conflict: ok)
  h8 wb[2][4];
  float bj[2];
#pragma unroll
  for (int jt = 0; jt < 2; ++jt) {
    const int col = w * 32 + jt * 16 + lrow;
    bj[jt] = bias[col];
#pragma unroll
    for (int ks = 0; ks < 4; ++ks)
      wb[jt][ks] = *(const h8*)(lds + 32768 + col * 256 + ks * 64 + (lane >> 4) * 16);
  }

  _Float16* cs = (_Float16*)(lds + 65536);
#pragma unroll
  for (int rt = 0; rt < 4; ++rt) {
    const int rowbase = row0 + rt * 16;
    if (rowbase >= N) break;             // block-uniform (tail block only)
    f4 acc[2] = {(f4){0.f,0.f,0.f,0.f}, (f4){0.f,0.f,0.f,0.f}};
#pragma unroll
    for (int ks = 0; ks < 4; ++ks) {
      const int r   = rt * 16 + lrow;
      const int cg0 = ks * 8 + (lane >> 4) * 2;
      const f4 a0 = *(const f4*)(lds + r * 512 + ((cg0 ^ (r & 7)) << 4));
      const f4 a1 = *(const f4*)(lds + r * 512 + (((cg0 + 1) ^ (r & 7)) << 4));
      h8 af;
      af[0]=(_Float16)a0.x; af[1]=(_Float16)a0.y; af[2]=(_Float16)a0.z; af[3]=(_Float16)a0.w;
      af[4]=(_Float16)a1.x; af[5]=(_Float16)a1.y; af[6]=(_Float16)a1.z; af[7]=(_Float16)a1.w;
      acc[0] = __builtin_amdgcn_mfma_f32_16x16x32_f16(af, wb[0][ks], acc[0], 0, 0, 0);
      acc[1] = __builtin_amdgcn_mfma_f32_16x16x32_f16(af, wb[1][ks], acc[1], 0, 0, 0);
    }
#pragma unroll
    for (int jt = 0; jt < 2; ++jt)
#pragma unroll
      for (int r = 0; r < 4; ++r)
        cs[(srow + r) * DD + w * 32 + jt * 16 + lrow] = (_Float16)(acc[jt][r] + bj[jt]);
    __syncthreads();
    const int frow = rowbase + (tid >> 4);
    if (frow < N) {
      const f4 v = *(const f4*)((char*)cs + tid * 16);
      *(f4*)((char*)h16 + (size_t)frow * 256 + (tid & 15) * 16) = v;
    }
    __syncthreads();
  }
}

// scan1: per-1024-chunk local exclusive scan of cnt -> rowptr, block sums -> bsum,
// dis = rsqrt(deg). (Global offsets boff added inline by consumers.)
__global__ __launch_bounds__(256) void scan1(const int* __restrict__ cnt,
    int* __restrict__ rowptr, int* __restrict__ bsum, float* __restrict__ dis, int N) {
  __shared__ int s[256];
  const int tid = threadIdx.x;
  const int idx = blockIdx.x * 1024 + tid * 4;
  int4 v = {0, 0, 0, 0};
  if (idx + 3 < N) v = *(const int4*)(cnt + idx);
  else {
    if (idx + 0 < N) v.x = cnt[idx];
    if (idx + 1 < N) v.y = cnt[idx + 1];
    if (idx + 2 < N) v.z = cnt[idx + 2];
  }
  if (idx + 0 < N) dis[idx + 0] = rsqrtf((float)(v.x + 1));
  if (idx + 1 < N) dis[idx + 1] = rsqrtf((float)(v.y + 1));
  if (idx + 2 < N) dis[idx + 2] = rsqrtf((float)(v.z + 1));
  if (idx + 3 < N) dis[idx + 3] = rsqrtf((float)(v.w + 1));
  const int mysum = v.x + v.y + v.z + v.w;
  s[tid] = mysum;
  __syncthreads();
  for (int off = 1; off < 256; off <<= 1) {
    int t = (tid >= off) ? s[tid - off] : 0;
    __syncthreads();
    s[tid] += t;
    __syncthreads();
  }
  if (tid == 255) bsum[blockIdx.x] = s[255];
  int p = s[tid] - mysum;
  if (idx + 0 < N) rowptr[idx + 0] = p; p += v.x;
  if (idx + 1 < N) rowptr[idx + 1] = p; p += v.y;
  if (idx + 2 < N) rowptr[idx + 2] = p; p += v.z;
  if (idx + 3 < N) rowptr[idx + 3] = p;
}

// scan2: exclusive scan of block sums -> boff; rowptr[N] = last block's local sum.
__global__ __launch_bounds__(256) void scan2(const int* __restrict__ bsum,
    int* __restrict__ boff, int* __restrict__ rowptr, int nb, int N) {
  __shared__ int s[256];
  const int tid = threadIdx.x;
  const int v = (tid < nb) ? bsum[tid] : 0;
  s[tid] = v;
  __syncthreads();
  for (int off = 1; off < 256; off <<= 1) {
    int t = (tid >= off) ? s[tid - off] : 0;
    __syncthreads();
    s[tid] += t;
    __syncthreads();
  }
  if (tid < nb) boff[tid] = s[tid] - v;
  if (tid == nb - 1) rowptr[N] = v;
}

// scatter edges into dst-grouped order; cnt doubles as a decrementing cursor.
__global__ void fill_csr(const int* __restrict__ src, const int* __restrict__ dst,
    const int* __restrict__ rowptr, const int* __restrict__ boff,
    int* __restrict__ cnt, int* __restrict__ esrc, int E) {
  int e = blockIdx.x * blockDim.x + threadIdx.x;
  if (e < E) {
    const int t = dst[e];
    const int p = rowptr[t] + boff[t >> 10] + atomicAdd(cnt + t, -1) - 1;
    esrc[p] = src[e];
  }
}

// per node: 32 threads each own 4 columns (8B fp16 gather); unroll-4 edge loop.
__global__ __launch_bounds__(256) void csr_agg(const int* __restrict__ esrc,
    const int* __restrict__ rowptr, const int* __restrict__ boff,
    const _Float16* __restrict__ h16, const float* __restrict__ dis,
    const float* __restrict__ root, float* __restrict__ out, int N) {
  int gid = blockIdx.x * blockDim.x + threadIdx.x;
  if (gid >= N * 32) return;
  const int n = gid >> 5, q = gid & 31;
  const float dt  = dis[n];
  const float inv = dt * dt;            // 1/deg
  const h4v* hv4 = reinterpret_cast<const h4v*>(h16);
  const float4 rv = reinterpret_cast<const float4*>(root)[q];
  const h4v hv = hv4[n * 32 + q];
  float4 acc;
  acc.x = fmaxf((float)hv[0] + rv.x, 0.0f) * inv;
  acc.y = fmaxf((float)hv[1] + rv.y, 0.0f) * inv;
  acc.z = fmaxf((float)hv[2] + rv.z, 0.0f) * inv;
  acc.w = fmaxf((float)hv[3] + rv.w, 0.0f) * inv;
  float4 ea = {0.f, 0.f, 0.f, 0.f};
  const int beg = rowptr[n] + boff[n >> 10];
  const int end = rowptr[n + 1] + boff[(n + 1) >> 10];
  int k = beg;
  for (; k + 3 < end; k += 4) {
    const int s0 = esrc[k], s1 = esrc[k + 1], s2 = esrc[k + 2], s3 = esrc[k + 3];
    const float w0 = dis[s0], w1 = dis[s1], w2 = dis[s2], w3 = dis[s3];
    const h4v g0 = hv4[s0 * 32 + q];
    const h4v g1 = hv4[s1 * 32 + q];
    const h4v g2 = hv4[s2 * 32 + q];
    const h4v g3 = hv4[s3 * 32 + q];
    ea.x += fmaxf((float)g0[0], 0.0f) * w0 + fmaxf((float)g1[0], 0.0f) * w1
          + fmaxf((float)g2[0], 0.0f) * w2 + fmaxf((float)g3[0], 0.0f) * w3;
    ea.y += fmaxf((float)g0[1], 0.0f) * w0 + fmaxf((float)g1[1], 0.0f) * w1
          + fmaxf((float)g2[1], 0.0f) * w2 + fmaxf((float)g3[1], 0.0f) * w3;
    ea.z += fmaxf((float)g0[2], 0.0f) * w0 + fmaxf((float)g1[2], 0.0f) * w1
          + fmaxf((float)g2[2], 0.0f) * w2 + fmaxf((float)g3[2], 0.0f) * w3;
    ea.w += fmaxf((float)g0[3], 0.0f) * w0 + fmaxf((float)g1[3], 0.0f) * w1
          + fmaxf((float)g2[3], 0.0f) * w2 + fmaxf((float)g3[3], 0.0f) * w3;
  }
  for (; k < end; ++k) {
    const int s0 = esrc[k];
    const float w0 = dis[s0];
    const h4v g0 = hv4[s0 * 32 + q];
    ea.x += fmaxf((float)g0[0], 0.0f) * w0;
    ea.y += fmaxf((float)g0[1], 0.0f) * w0;
    ea.z += fmaxf((float)g0[2], 0.0f) * w0;
    ea.w += fmaxf((float)g0[3], 0.0f) * w0;
  }
  acc.x += ea.x * dt;
  acc.y += ea.y * dt;
  acc.z += ea.z * dt;
  acc.w += ea.w * dt;
  reinterpret_cast<float4*>(out)[gid] = acc;
}

extern "C" void kernel_launch(void* const* d_in, const int* in_sizes, int n_in,
                              void* d_out, int out_size, void* d_ws, size_t ws_size,
                              hipStream_t stream) {
  const float* x    = (const float*)d_in[0];
  const int*   src  = (const int*)d_in[1];
  const int*   dst  = (const int*)d_in[2];
  const float* W    = (const float*)d_in[3];
  const float* bias = (const float*)d_in[4];
  const float* root = (const float*)d_in[5];
  float* out = (float*)d_out;
  const int N = in_sizes[0] / DD;
  const int E = in_sizes[1];

  char* ws = (char*)d_ws;
  size_t off = 0;
  _Float16* h16 = (_Float16*)(ws + off); off += (size_t)N * DD * 2;
  int*   cnt    = (int*)  (ws + off); off += (size_t)N * 4;
  float* dis    = (float*)(ws + off); off += (size_t)N * 4;
  int*   rowptr = (int*)  (ws + off); off += (size_t)(N + 2) * 4;
  int*   esrc   = (int*)  (ws + off); off += (size_t)E * 4;
  int*   bsum   = (int*)  (ws + off); off += 256 * 4;
  int*   boff   = (int*)  (ws + off); off += 256 * 4;
  _Float16* Wh  = (_Float16*)(ws + off); off += (size_t)DD * DD * 2;

  const int nb  = (N + 1023) / 1024;   // 49
  const int nbt = (N + 63) / 64;       // 782 row-tiles of 64
  prep<<<128, 256, 0, stream>>>(W, Wh, cnt, N);
  gemm_mfma<<<nbt, 256, 0, stream>>>(x, Wh, bias, h16, dst, cnt, E, N);
  scan1<<<nb, 256, 0, stream>>>(cnt, rowptr, bsum, dis, N);
  scan2<<<1, 256, 0, stream>>>(bsum, boff, rowptr, nb, N);
  fill_csr<<<(E + 255) / 256, 256, 0, stream>>>(src, dst, rowptr, boff, cnt, esrc, E);
  csr_agg<<<(N * 32 + 255) / 256, 256, 0, stream>>>(esrc, rowptr, boff, h16, dis, root, out, N);
}

// Round 11
// 86.829 us; speedup vs baseline: 2.9144x; 1.2447x over previous
//
#include <hip/hip_runtime.h>

#define DD 128

typedef _Float16 h8 __attribute__((ext_vector_type(8)));
typedef float f4 __attribute__((ext_vector_type(4)));

// prep: W (fp32) -> Wh (fp16), zero degree counters.
__global__ __launch_bounds__(256) void prep(const float* __restrict__ W,
    _Float16* __restrict__ Wh, int* __restrict__ cnt, int N) {
  const int gid = blockIdx.x * blockDim.x + threadIdx.x;
  const int stride = gridDim.x * blockDim.x;
  for (int i = gid; i < DD * DD; i += stride) Wh[i] = (_Float16)W[i];
  for (int i = gid; i < N; i += stride) cnt[i] = 0;
}

// h16 = fp16(x @ W.T + b). Block = 64 rows; Wh + x staged via global_load_lds.
// Prologue: slot-recording in-degree count — slot[e] = arrival index within
// dst bucket, so fill_csr needs NO atomics (R8/R9 WRITE_SIZE showed the two
// atomic passes generate ~30MB of TCC RMW traffic each — the real cost).
__global__ __launch_bounds__(256) void gemm_mfma(const float* __restrict__ x,
    const _Float16* __restrict__ Wh, const float* __restrict__ bias,
    _Float16* __restrict__ h16, const int* __restrict__ dst,
    int* __restrict__ cnt, int* __restrict__ slot, int E, int N) {
  __shared__ __align__(16) char lds[32768 + 32768 + 4096]; // xs | whs | cs
  const int tid = threadIdx.x;
  const int gid = blockIdx.x * 256 + tid;
  const int gsz = gridDim.x * 256;
  for (int e = gid; e < E; e += gsz) slot[e] = atomicAdd(cnt + dst[e], 1);

  const int lane = tid & 63;
  const int w    = tid >> 6;          // wave id -> cols w*32..+32
  const int lrow = lane & 15;
  const int srow = (lane >> 4) << 2;
  const int row0 = blockIdx.x * 64;

  // stage Wh: 32KB linear, fully coalesced
#pragma unroll
  for (int i = 0; i < 8; ++i) {
    const char* s = (const char*)Wh + i * 4096 + tid * 16;
    __builtin_amdgcn_global_load_lds(
        (const __attribute__((address_space(1))) void*)s,
        (__attribute__((address_space(3))) void*)(lds + 32768 + i * 4096 + ((tid >> 6) << 10)),
        16, 0, 0);
  }
  // stage x: 64 rows x 512B; LDS linear, global source 16B-group swizzled
#pragma unroll
  for (int i = 0; i < 8; ++i) {
    const int ol = i * 4096 + tid * 16;
    const int r  = ol >> 9;               // staged row 0..63
    const int cg = (ol >> 4) & 31;        // 16B col-group
    int grow = row0 + r; if (grow >= N) grow = N - 1;
    const char* s = (const char*)x + (size_t)grow * 512 + ((cg ^ (r & 7)) << 4);
    __builtin_amdgcn_global_load_lds(
        (const __attribute__((address_space(1))) void*)s,
        (__attribute__((address_space(3))) void*)(lds + i * 4096 + ((tid >> 6) << 10)),
        16, 0, 0);
  }
  __syncthreads();

  // W fragments + bias from LDS, once per block
  h8 wb[2][4];
  float bj[2];
#pragma unroll
  for (int jt = 0; jt < 2; ++jt) {
    const int col = w * 32 + jt * 16 + lrow;
    bj[jt] = bias[col];
#pragma unroll
    for (int ks = 0; ks < 4; ++ks)
      wb[jt][ks] = *(const h8*)(lds + 32768 + col * 256 + ks * 64 + (lane >> 4) * 16);
  }

  _Float16* cs = (_Float16*)(lds + 65536);
#pragma unroll
  for (int rt = 0; rt < 4; ++rt) {
    const int rowbase = row0 + rt * 16;
    if (rowbase >= N) break;             // block-uniform (tail block only)
    f4 acc[2] = {(f4){0.f,0.f,0.f,0.f}, (f4){0.f,0.f,0.f,0.f}};
#pragma unroll
    for (int ks = 0; ks < 4; ++ks) {
      const int r   = rt * 16 + lrow;
      const int cg0 = ks * 8 + (lane >> 4) * 2;
      const f4 a0 = *(const f4*)(lds + r * 512 + ((cg0 ^ (r & 7)) << 4));
      const f4 a1 = *(const f4*)(lds + r * 512 + (((cg0 + 1) ^ (r & 7)) << 4));
      h8 af;
      af[0]=(_Float16)a0.x; af[1]=(_Float16)a0.y; af[2]=(_Float16)a0.z; af[3]=(_Float16)a0.w;
      af[4]=(_Float16)a1.x; af[5]=(_Float16)a1.y; af[6]=(_Float16)a1.z; af[7]=(_Float16)a1.w;
      acc[0] = __builtin_amdgcn_mfma_f32_16x16x32_f16(af, wb[0][ks], acc[0], 0, 0, 0);
      acc[1] = __builtin_amdgcn_mfma_f32_16x16x32_f16(af, wb[1][ks], acc[1], 0, 0, 0);
    }
#pragma unroll
    for (int jt = 0; jt < 2; ++jt)
#pragma unroll
      for (int r = 0; r < 4; ++r)
        cs[(srow + r) * DD + w * 32 + jt * 16 + lrow] = (_Float16)(acc[jt][r] + bj[jt]);
    __syncthreads();
    const int frow = rowbase + (tid >> 4);
    if (frow < N) {
      const f4 v = *(const f4*)((char*)cs + tid * 16);
      *(f4*)((char*)h16 + (size_t)frow * 256 + (tid & 15) * 16) = v;
    }
    __syncthreads();
  }
}

// scan1: per-1024-chunk local exclusive scan of cnt -> rowptr, block sums -> bsum,
// dis = rsqrt(deg). (Global offsets boff added inline by consumers.)
__global__ __launch_bounds__(256) void scan1(const int* __restrict__ cnt,
    int* __restrict__ rowptr, int* __restrict__ bsum, float* __restrict__ dis, int N) {
  __shared__ int s[256];
  const int tid = threadIdx.x;
  const int idx = blockIdx.x * 1024 + tid * 4;
  int4 v = {0, 0, 0, 0};
  if (idx + 3 < N) v = *(const int4*)(cnt + idx);
  else {
    if (idx + 0 < N) v.x = cnt[idx];
    if (idx + 1 < N) v.y = cnt[idx + 1];
    if (idx + 2 < N) v.z = cnt[idx + 2];
  }
  if (idx + 0 < N) dis[idx + 0] = rsqrtf((float)(v.x + 1));
  if (idx + 1 < N) dis[idx + 1] = rsqrtf((float)(v.y + 1));
  if (idx + 2 < N) dis[idx + 2] = rsqrtf((float)(v.z + 1));
  if (idx + 3 < N) dis[idx + 3] = rsqrtf((float)(v.w + 1));
  const int mysum = v.x + v.y + v.z + v.w;
  s[tid] = mysum;
  __syncthreads();
  for (int off = 1; off < 256; off <<= 1) {
    int t = (tid >= off) ? s[tid - off] : 0;
    __syncthreads();
    s[tid] += t;
    __syncthreads();
  }
  if (tid == 255) bsum[blockIdx.x] = s[255];
  int p = s[tid] - mysum;
  if (idx + 0 < N) rowptr[idx + 0] = p; p += v.x;
  if (idx + 1 < N) rowptr[idx + 1] = p; p += v.y;
  if (idx + 2 < N) rowptr[idx + 2] = p; p += v.z;
  if (idx + 3 < N) rowptr[idx + 3] = p;
}

// scan2: exclusive scan of block sums -> boff; rowptr[N] = last block's local sum.
__global__ __launch_bounds__(256) void scan2(const int* __restrict__ bsum,
    int* __restrict__ boff, int* __restrict__ rowptr, int nb, int N) {
  __shared__ int s[256];
  const int tid = threadIdx.x;
  const int v = (tid < nb) ? bsum[tid] : 0;
  s[tid] = v;
  __syncthreads();
  for (int off = 1; off < 256; off <<= 1) {
    int t = (tid >= off) ? s[tid - off] : 0;
    __syncthreads();
    s[tid] += t;
    __syncthreads();
  }
  if (tid < nb) boff[tid] = s[tid] - v;
  if (tid == nb - 1) rowptr[N] = v;
}

// scatter edges into dst-grouped order — ATOMIC-FREE: slot[e] recorded in gemm's
// counting pass gives each edge its unique in-bucket index.
__global__ void fill_csr(const int* __restrict__ src, const int* __restrict__ dst,
    const int* __restrict__ rowptr, const int* __restrict__ boff,
    const int* __restrict__ slot, int* __restrict__ esrc, int E) {
  int e = blockIdx.x * blockDim.x + threadIdx.x;
  if (e < E) {
    const int t = dst[e];
    esrc[rowptr[t] + boff[t >> 10] + slot[e]] = src[e];
  }
}

// per node: 16 threads each own 8 columns (16B h8 gather — half the load
// instructions of the 32-thread/8B version); unroll-4 edge loop.
__global__ __launch_bounds__(256) void csr_agg(const int* __restrict__ esrc,
    const int* __restrict__ rowptr, const int* __restrict__ boff,
    const _Float16* __restrict__ h16, const float* __restrict__ dis,
    const float* __restrict__ root, float* __restrict__ out, int N) {
  int gid = blockIdx.x * blockDim.x + threadIdx.x;
  if (gid >= N * 16) return;
  const int n = gid >> 4, q = gid & 15;
  const float dt  = dis[n];
  const float inv = dt * dt;            // 1/deg
  const h8* hv8 = reinterpret_cast<const h8*>(h16);
  const f4 r0 = reinterpret_cast<const f4*>(root)[q * 2];
  const f4 r1 = reinterpret_cast<const f4*>(root)[q * 2 + 1];
  const h8 hv = hv8[n * 16 + q];
  float acc[8];
  acc[0] = fmaxf((float)hv[0] + r0.x, 0.0f) * inv;
  acc[1] = fmaxf((float)hv[1] + r0.y, 0.0f) * inv;
  acc[2] = fmaxf((float)hv[2] + r0.z, 0.0f) * inv;
  acc[3] = fmaxf((float)hv[3] + r0.w, 0.0f) * inv;
  acc[4] = fmaxf((float)hv[4] + r1.x, 0.0f) * inv;
  acc[5] = fmaxf((float)hv[5] + r1.y, 0.0f) * inv;
  acc[6] = fmaxf((float)hv[6] + r1.z, 0.0f) * inv;
  acc[7] = fmaxf((float)hv[7] + r1.w, 0.0f) * inv;
  float ea[8] = {0.f, 0.f, 0.f, 0.f, 0.f, 0.f, 0.f, 0.f};
  const int beg = rowptr[n] + boff[n >> 10];
  const int end = rowptr[n + 1] + boff[(n + 1) >> 10];
  int k = beg;
  for (; k + 3 < end; k += 4) {
    const int s0 = esrc[k], s1 = esrc[k + 1], s2 = esrc[k + 2], s3 = esrc[k + 3];
    const float w0 = dis[s0], w1 = dis[s1], w2 = dis[s2], w3 = dis[s3];
    const h8 g0 = hv8[s0 * 16 + q];
    const h8 g1 = hv8[s1 * 16 + q];
    const h8 g2 = hv8[s2 * 16 + q];
    const h8 g3 = hv8[s3 * 16 + q];
#pragma unroll
    for (int j = 0; j < 8; ++j)
      ea[j] += fmaxf((float)g0[j], 0.0f) * w0 + fmaxf((float)g1[j], 0.0f) * w1
             + fmaxf((float)g2[j], 0.0f) * w2 + fmaxf((float)g3[j], 0.0f) * w3;
  }
  for (; k < end; ++k) {
    const int s0 = esrc[k];
    const float w0 = dis[s0];
    const h8 g0 = hv8[s0 * 16 + q];
#pragma unroll
    for (int j = 0; j < 8; ++j) ea[j] += fmaxf((float)g0[j], 0.0f) * w0;
  }
  f4 o0, o1;
  o0.x = acc[0] + ea[0] * dt; o0.y = acc[1] + ea[1] * dt;
  o0.z = acc[2] + ea[2] * dt; o0.w = acc[3] + ea[3] * dt;
  o1.x = acc[4] + ea[4] * dt; o1.y = acc[5] + ea[5] * dt;
  o1.z = acc[6] + ea[6] * dt; o1.w = acc[7] + ea[7] * dt;
  reinterpret_cast<f4*>(out)[n * 32 + q * 2]     = o0;
  reinterpret_cast<f4*>(out)[n * 32 + q * 2 + 1] = o1;
}

extern "C" void kernel_launch(void* const* d_in, const int* in_sizes, int n_in,
                              void* d_out, int out_size, void* d_ws, size_t ws_size,
                              hipStream_t stream) {
  const float* x    = (const float*)d_in[0];
  const int*   src  = (const int*)d_in[1];
  const int*   dst  = (const int*)d_in[2];
  const float* W    = (const float*)d_in[3];
  const float* bias = (const float*)d_in[4];
  const float* root = (const float*)d_in[5];
  float* out = (float*)d_out;
  const int N = in_sizes[0] / DD;
  const int E = in_sizes[1];

  char* ws = (char*)d_ws;
  size_t off = 0;
  _Float16* h16 = (_Float16*)(ws + off); off += (size_t)N * DD * 2;
  int*   cnt    = (int*)  (ws + off); off += (size_t)N * 4;
  float* dis    = (float*)(ws + off); off += (size_t)N * 4;
  int*   rowptr = (int*)  (ws + off); off += (size_t)(N + 2) * 4;
  int*   esrc   = (int*)  (ws + off); off += (size_t)E * 4;
  int*   slot   = (int*)  (ws + off); off += (size_t)E * 4;
  int*   bsum   = (int*)  (ws + off); off += 256 * 4;
  int*   boff   = (int*)  (ws + off); off += 256 * 4;
  _Float16* Wh  = (_Float16*)(ws + off); off += (size_t)DD * DD * 2;

  const int nb  = (N + 1023) / 1024;   // 49
  const int nbt = (N + 63) / 64;       // 782 row-tiles of 64
  prep<<<128, 256, 0, stream>>>(W, Wh, cnt, N);
  gemm_mfma<<<nbt, 256, 0, stream>>>(x, Wh, bias, h16, dst, cnt, slot, E, N);
  scan1<<<nb, 256, 0, stream>>>(cnt, rowptr, bsum, dis, N);
  scan2<<<1, 256, 0, stream>>>(bsum, boff, rowptr, nb, N);
  fill_csr<<<(E + 255) / 256, 256, 0, stream>>>(src, dst, rowptr, boff, slot, esrc, E);
  csr_agg<<<(N * 16 + 255) / 256, 256, 0, stream>>>(esrc, rowptr, boff, h16, dis, root, out, N);
}

// Round 12
// 85.985 us; speedup vs baseline: 2.9430x; 1.0098x over previous
//
#include <hip/hip_runtime.h>

#define DD 128

typedef _Float16 h8 __attribute__((ext_vector_type(8)));
typedef float f4 __attribute__((ext_vector_type(4)));

// prep: W (fp32) -> Wh (fp16), zero degree counters.
__global__ __launch_bounds__(256) void prep(const float* __restrict__ W,
    _Float16* __restrict__ Wh, int* __restrict__ cnt, int N) {
  const int gid = blockIdx.x * blockDim.x + threadIdx.x;
  const int stride = gridDim.x * blockDim.x;
  for (int i = gid; i < DD * DD; i += stride) Wh[i] = (_Float16)W[i];
  for (int i = gid; i < N; i += stride) cnt[i] = 0;
}

// h16 = fp16(x @ W.T + b). Block = 64 rows; Wh + x staged via global_load_lds.
// Prologue: slot-recording in-degree count (slot[e] = arrival index in dst
// bucket) so the CSR scatter needs no second atomic pass.
__global__ __launch_bounds__(256) void gemm_mfma(const float* __restrict__ x,
    const _Float16* __restrict__ Wh, const float* __restrict__ bias,
    _Float16* __restrict__ h16, const int* __restrict__ dst,
    int* __restrict__ cnt, int* __restrict__ slot, int E, int N) {
  __shared__ __align__(16) char lds[32768 + 32768 + 4096]; // xs | whs | cs
  const int tid = threadIdx.x;
  const int gid = blockIdx.x * 256 + tid;
  const int gsz = gridDim.x * 256;
  for (int e = gid; e < E; e += gsz) slot[e] = atomicAdd(cnt + dst[e], 1);

  const int lane = tid & 63;
  const int w    = tid >> 6;          // wave id -> cols w*32..+32
  const int lrow = lane & 15;
  const int srow = (lane >> 4) << 2;
  const int row0 = blockIdx.x * 64;

  // stage Wh: 32KB linear, fully coalesced
#pragma unroll
  for (int i = 0; i < 8; ++i) {
    const char* s = (const char*)Wh + i * 4096 + tid * 16;
    __builtin_amdgcn_global_load_lds(
        (const __attribute__((address_space(1))) void*)s,
        (__attribute__((address_space(3))) void*)(lds + 32768 + i * 4096 + ((tid >> 6) << 10)),
        16, 0, 0);
  }
  // stage x: 64 rows x 512B; LDS linear, global source 16B-group swizzled
#pragma unroll
  for (int i = 0; i < 8; ++i) {
    const int ol = i * 4096 + tid * 16;
    const int r  = ol >> 9;               // staged row 0..63
    const int cg = (ol >> 4) & 31;        // 16B col-group
    int grow = row0 + r; if (grow >= N) grow = N - 1;
    const char* s = (const char*)x + (size_t)grow * 512 + ((cg ^ (r & 7)) << 4);
    __builtin_amdgcn_global_load_lds(
        (const __attribute__((address_space(1))) void*)s,
        (__attribute__((address_space(3))) void*)(lds + i * 4096 + ((tid >> 6) << 10)),
        16, 0, 0);
  }
  __syncthreads();

  // W fragments + bias from LDS, once per block
  h8 wb[2][4];
  float bj[2];
#pragma unroll
  for (int jt = 0; jt < 2; ++jt) {
    const int col = w * 32 + jt * 16 + lrow;
    bj[jt] = bias[col];
#pragma unroll
    for (int ks = 0; ks < 4; ++ks)
      wb[jt][ks] = *(const h8*)(lds + 32768 + col * 256 + ks * 64 + (lane >> 4) * 16);
  }

  _Float16* cs = (_Float16*)(lds + 65536);
#pragma unroll
  for (int rt = 0; rt < 4; ++rt) {
    const int rowbase = row0 + rt * 16;
    if (rowbase >= N) break;             // block-uniform (tail block only)
    f4 acc[2] = {(f4){0.f,0.f,0.f,0.f}, (f4){0.f,0.f,0.f,0.f}};
#pragma unroll
    for (int ks = 0; ks < 4; ++ks) {
      const int r   = rt * 16 + lrow;
      const int cg0 = ks * 8 + (lane >> 4) * 2;
      const f4 a0 = *(const f4*)(lds + r * 512 + ((cg0 ^ (r & 7)) << 4));
      const f4 a1 = *(const f4*)(lds + r * 512 + (((cg0 + 1) ^ (r & 7)) << 4));
      h8 af;
      af[0]=(_Float16)a0.x; af[1]=(_Float16)a0.y; af[2]=(_Float16)a0.z; af[3]=(_Float16)a0.w;
      af[4]=(_Float16)a1.x; af[5]=(_Float16)a1.y; af[6]=(_Float16)a1.z; af[7]=(_Float16)a1.w;
      acc[0] = __builtin_amdgcn_mfma_f32_16x16x32_f16(af, wb[0][ks], acc[0], 0, 0, 0);
      acc[1] = __builtin_amdgcn_mfma_f32_16x16x32_f16(af, wb[1][ks], acc[1], 0, 0, 0);
    }
#pragma unroll
    for (int jt = 0; jt < 2; ++jt)
#pragma unroll
      for (int r = 0; r < 4; ++r)
        cs[(srow + r) * DD + w * 32 + jt * 16 + lrow] = (_Float16)(acc[jt][r] + bj[jt]);
    __syncthreads();
    const int frow = rowbase + (tid >> 4);
    if (frow < N) {
      const f4 v = *(const f4*)((char*)cs + tid * 16);
      *(f4*)((char*)h16 + (size_t)frow * 256 + (tid & 15) * 16) = v;
    }
    __syncthreads();
  }
}

// scan1: per-1024-chunk local exclusive scan of cnt -> rowptr, block sums -> bsum,
// dis = rsqrt(deg). Global block offsets are computed inline by consumers.
__global__ __launch_bounds__(256) void scan1(const int* __restrict__ cnt,
    int* __restrict__ rowptr, int* __restrict__ bsum, float* __restrict__ dis, int N) {
  __shared__ int s[256];
  const int tid = threadIdx.x;
  const int idx = blockIdx.x * 1024 + tid * 4;
  int4 v = {0, 0, 0, 0};
  if (idx + 3 < N) v = *(const int4*)(cnt + idx);
  else {
    if (idx + 0 < N) v.x = cnt[idx];
    if (idx + 1 < N) v.y = cnt[idx + 1];
    if (idx + 2 < N) v.z = cnt[idx + 2];
  }
  if (idx + 0 < N) dis[idx + 0] = rsqrtf((float)(v.x + 1));
  if (idx + 1 < N) dis[idx + 1] = rsqrtf((float)(v.y + 1));
  if (idx + 2 < N) dis[idx + 2] = rsqrtf((float)(v.z + 1));
  if (idx + 3 < N) dis[idx + 3] = rsqrtf((float)(v.w + 1));
  const int mysum = v.x + v.y + v.z + v.w;
  s[tid] = mysum;
  __syncthreads();
  for (int off = 1; off < 256; off <<= 1) {
    int t = (tid >= off) ? s[tid - off] : 0;
    __syncthreads();
    s[tid] += t;
    __syncthreads();
  }
  if (tid == 255) bsum[blockIdx.x] = s[255];
  int p = s[tid] - mysum;
  if (idx + 0 < N) rowptr[idx + 0] = p; p += v.x;
  if (idx + 1 < N) rowptr[idx + 1] = p; p += v.y;
  if (idx + 2 < N) rowptr[idx + 2] = p; p += v.z;
  if (idx + 3 < N) rowptr[idx + 3] = p;
}

// wave-0 exclusive scan of bsum[0..nb) into LDS (nb <= 64)
__device__ __forceinline__ void boff_scan(const int* __restrict__ bsum,
    int* __restrict__ sbof, int tid, int nb) {
  if (tid < 64) {
    const int v = (tid < nb) ? bsum[tid] : 0;
    int incl = v;
#pragma unroll
    for (int off = 1; off < 64; off <<= 1) {
      const int t = __shfl_up(incl, off);
      if (tid >= off) incl += t;
    }
    sbof[tid] = incl - v;
  }
  __syncthreads();
}

// scatter edges into dst-grouped order — atomic-free (slot from counting pass);
// 4 edges/thread via int4; block offsets scanned inline (scan2 eliminated).
__global__ __launch_bounds__(256) void fill_csr(const int* __restrict__ src,
    const int* __restrict__ dst, const int* __restrict__ rowptr,
    const int* __restrict__ bsum, const int* __restrict__ slot,
    int* __restrict__ esrc, int E, int nb) {
  __shared__ int sbof[64];
  const int tid = threadIdx.x;
  boff_scan(bsum, sbof, tid, nb);
  const int e4 = blockIdx.x * 256 + tid;
  const int e  = e4 * 4;
  if (e + 3 < E) {
    const int4 s4 = ((const int4*)src)[e4];
    const int4 d4 = ((const int4*)dst)[e4];
    const int4 l4 = ((const int4*)slot)[e4];
    esrc[rowptr[d4.x] + sbof[d4.x >> 10] + l4.x] = s4.x;
    esrc[rowptr[d4.y] + sbof[d4.y >> 10] + l4.y] = s4.y;
    esrc[rowptr[d4.z] + sbof[d4.z >> 10] + l4.z] = s4.z;
    esrc[rowptr[d4.w] + sbof[d4.w >> 10] + l4.w] = s4.w;
  } else if (e < E) {
    for (int i = e; i < E; ++i) {
      const int t = dst[i];
      esrc[rowptr[t] + sbof[t >> 10] + slot[i]] = src[i];
    }
  }
}

// per node: 16 threads each own 8 columns (16B h8 gather); unroll-4 edge loop;
// block offsets scanned inline; end at n=N-1 is E (rowptr[N] not materialized).
__global__ __launch_bounds__(256) void csr_agg(const int* __restrict__ esrc,
    const int* __restrict__ rowptr, const int* __restrict__ bsum,
    const _Float16* __restrict__ h16, const float* __restrict__ dis,
    const float* __restrict__ root, float* __restrict__ out, int N, int E, int nb) {
  __shared__ int sbof[64];
  const int tid = threadIdx.x;
  boff_scan(bsum, sbof, tid, nb);
  int gid = blockIdx.x * 256 + tid;
  if (gid >= N * 16) return;
  const int n = gid >> 4, q = gid & 15;
  const float dt  = dis[n];
  const float inv = dt * dt;            // 1/deg
  const h8* hv8 = reinterpret_cast<const h8*>(h16);
  const f4 r0 = reinterpret_cast<const f4*>(root)[q * 2];
  const f4 r1 = reinterpret_cast<const f4*>(root)[q * 2 + 1];
  const h8 hv = hv8[n * 16 + q];
  float acc[8];
  acc[0] = fmaxf((float)hv[0] + r0.x, 0.0f) * inv;
  acc[1] = fmaxf((float)hv[1] + r0.y, 0.0f) * inv;
  acc[2] = fmaxf((float)hv[2] + r0.z, 0.0f) * inv;
  acc[3] = fmaxf((float)hv[3] + r0.w, 0.0f) * inv;
  acc[4] = fmaxf((float)hv[4] + r1.x, 0.0f) * inv;
  acc[5] = fmaxf((float)hv[5] + r1.y, 0.0f) * inv;
  acc[6] = fmaxf((float)hv[6] + r1.z, 0.0f) * inv;
  acc[7] = fmaxf((float)hv[7] + r1.w, 0.0f) * inv;
  float ea[8] = {0.f, 0.f, 0.f, 0.f, 0.f, 0.f, 0.f, 0.f};
  const int beg = rowptr[n] + sbof[n >> 10];
  const int end = (n == N - 1) ? E : rowptr[n + 1] + sbof[(n + 1) >> 10];
  int k = beg;
  for (; k + 3 < end; k += 4) {
    const int s0 = esrc[k], s1 = esrc[k + 1], s2 = esrc[k + 2], s3 = esrc[k + 3];
    const float w0 = dis[s0], w1 = dis[s1], w2 = dis[s2], w3 = dis[s3];
    const h8 g0 = hv8[s0 * 16 + q];
    const h8 g1 = hv8[s1 * 16 + q];
    const h8 g2 = hv8[s2 * 16 + q];
    const h8 g3 = hv8[s3 * 16 + q];
#pragma unroll
    for (int j = 0; j < 8; ++j)
      ea[j] += fmaxf((float)g0[j], 0.0f) * w0 + fmaxf((float)g1[j], 0.0f) * w1
             + fmaxf((float)g2[j], 0.0f) * w2 + fmaxf((float)g3[j], 0.0f) * w3;
  }
  for (; k < end; ++k) {
    const int s0 = esrc[k];
    const float w0 = dis[s0];
    const h8 g0 = hv8[s0 * 16 + q];
#pragma unroll
    for (int j = 0; j < 8; ++j) ea[j] += fmaxf((float)g0[j], 0.0f) * w0;
  }
  f4 o0, o1;
  o0.x = acc[0] + ea[0] * dt; o0.y = acc[1] + ea[1] * dt;
  o0.z = acc[2] + ea[2] * dt; o0.w = acc[3] + ea[3] * dt;
  o1.x = acc[4] + ea[4] * dt; o1.y = acc[5] + ea[5] * dt;
  o1.z = acc[6] + ea[6] * dt; o1.w = acc[7] + ea[7] * dt;
  reinterpret_cast<f4*>(out)[n * 32 + q * 2]     = o0;
  reinterpret_cast<f4*>(out)[n * 32 + q * 2 + 1] = o1;
}

extern "C" void kernel_launch(void* const* d_in, const int* in_sizes, int n_in,
                              void* d_out, int out_size, void* d_ws, size_t ws_size,
                              hipStream_t stream) {
  const float* x    = (const float*)d_in[0];
  const int*   src  = (const int*)d_in[1];
  const int*   dst  = (const int*)d_in[2];
  const float* W    = (const float*)d_in[3];
  const float* bias = (const float*)d_in[4];
  const float* root = (const float*)d_in[5];
  float* out = (float*)d_out;
  const int N = in_sizes[0] / DD;
  const int E = in_sizes[1];

  char* ws = (char*)d_ws;
  size_t off = 0;
  _Float16* h16 = (_Float16*)(ws + off); off += (size_t)N * DD * 2;
  int*   cnt    = (int*)  (ws + off); off += (size_t)N * 4;
  float* dis    = (float*)(ws + off); off += (size_t)N * 4;
  int*   rowptr = (int*)  (ws + off); off += (size_t)(N + 2) * 4;
  int*   esrc   = (int*)  (ws + off); off += (size_t)E * 4;
  int*   slot   = (int*)  (ws + off); off += (size_t)E * 4;
  int*   bsum   = (int*)  (ws + off); off += 256 * 4;
  _Float16* Wh  = (_Float16*)(ws + off); off += (size_t)DD * DD * 2;

  const int nb  = (N + 1023) / 1024;   // 49
  const int nbt = (N + 63) / 64;       // 782 row-tiles of 64
  prep<<<128, 256, 0, stream>>>(W, Wh, cnt, N);
  gemm_mfma<<<nbt, 256, 0, stream>>>(x, Wh, bias, h16, dst, cnt, slot, E, N);
  scan1<<<nb, 256, 0, stream>>>(cnt, rowptr, bsum, dis, N);
  fill_csr<<<((E + 3) / 4 + 255) / 256, 256, 0, stream>>>(src, dst, rowptr, bsum, slot, esrc, E, nb);
  csr_agg<<<(N * 16 + 255) / 256, 256, 0, stream>>>(esrc, rowptr, bsum, h16, dis, root, out, N, E, nb);
}